// Round 12
// baseline (398.329 us; speedup 1.0000x reference)
//
#include <hip/hip_runtime.h>

#define HH 512
#define WW 512
#define NPIX (HH * WW)          // 262144
#define NIMG 16
#define KPTS 1024
#define NWORDS (NPIX / 64)      // 4096 u64 mask words per image
#define IMGW 8192               // u32 words per image region in ws (32 KB)
#define CNT_WORD 1536           // completion counter: image-0 region word 1536

// ---------------------------------------------------------------------------
// Kernel 1: binarize + uniform LBP (P=8,R=1) — PURE BOOLEAN form. (unchanged)
// ---------------------------------------------------------------------------
__global__ void lbp_kernel(const float* __restrict__ mo,
                           const float* __restrict__ lb,
                           unsigned long long* __restrict__ maskbits) {
    int m = blockIdx.y;                    // image 0..15: even=pred, odd=mask
    int pix = blockIdx.x * blockDim.x + threadIdx.x;   // 0..262143
    int r = pix >> 9, c = pix & 511;
    int sample = m >> 1;
    const float* img = (m & 1) ? (lb + sample * NPIX) : (mo + sample * NPIX);
    float thr = (m & 1) ? 0.5f : 0.0f;     // sigmoid(x)>0.5 <=> x>0

    int rm = r - (r > 0), rp = r + (r < HH - 1);
    int cm = c - (c > 0), cp = c + (c < WW - 1);
    const float* rowm = img + rm * WW;
    const float* row0 = img + r  * WW;
    const float* rowp = img + rp * WW;

    bool bmm = rowm[cm] > thr, bm0 = rowm[c] > thr, bmp = rowm[cp] > thr;
    bool b0m = row0[cm] > thr, b00 = row0[c] > thr, b0p = row0[cp] > thr;
    bool bpm = rowp[cm] > thr, bp0 = rowp[c] > thr, bpp = rowp[cp] > thr;

    bool r0e = (r == 0), c0e = (c == 0);
    bool t2m = r0e ? bpm : b0m;    // B(row2, cm)
    bool t2c = r0e ? bp0 : b00;    // B(row2, c)
    bool t2p = r0e ? bpp : b0p;    // B(row2, cp)
    bool mc2 = c0e ? bmp : bm0;    // B(rm,  col2)
    bool tc2 = c0e ? t2p : t2c;    // B(row2,col2)
    bool zc2 = c0e ? b0p : b00;    // B(r,   col2)
    bool pc2 = c0e ? bpp : bp0;    // B(rp,  col2)

    unsigned bb =
        (b0p                     ?   1u : 0u)
      | ((bm0 & bmp & t2c & t2p) ?   2u : 0u)
      | (bm0                     ?   4u : 0u)
      | ((bmm & mc2 & t2m & tc2) ?   8u : 0u)
      | (b0m                     ?  16u : 0u)
      | ((b0m & zc2 & bpm & pc2) ?  32u : 0u)
      | (bp0                     ?  64u : 0u)
      | ((b0p & bp0 & bpp)       ? 128u : 0u);

    unsigned rol = ((bb << 1) | (bb >> 7)) & 0xFFu;
    int changes = __popc(bb ^ rol);
    int s = __popc(bb);
    bool maskbit = b00 && (changes <= 2) && (s < 5);   // lbp < THR(=5)

    unsigned long long w = __ballot(maskbit);
    if ((threadIdx.x & 63) == 0)
        maskbits[m * NWORDS + (pix >> 6)] = w;
}

// ---------------------------------------------------------------------------
// Kernel 2 (FUSED select + mst): grid 16 x 256. (unchanged from R10/R11,
// plus: block 0 zeroes the recover completion counter after its select
// phase — word CNT_WORD of image 0's region is touchable only by block 0's
// own select reads, which are already done; stream order publishes the
// zero to recover.)
// ---------------------------------------------------------------------------
typedef short v2s __attribute__((ext_vector_type(2)));
typedef unsigned u32x4 __attribute__((ext_vector_type(4)));

__device__ __forceinline__ int dist2_packed(unsigned a, unsigned b) {
#if __has_builtin(__builtin_amdgcn_sdot2)
    v2s d = __builtin_bit_cast(v2s, a) - __builtin_bit_cast(v2s, b);
    return __builtin_amdgcn_sdot2(d, d, 0, false);
#else
    int dr = (int)(a >> 16) - (int)(b >> 16);
    int dc = (int)(a & 0xFFFFu) - (int)(b & 0xFFFFu);
    return __mul24(dr, dr) + __mul24(dc, dc);
#endif
}

template <int CTRL>
__device__ __forceinline__ unsigned umin_dpp(unsigned x) {
    unsigned o = (unsigned)__builtin_amdgcn_update_dpp((int)x, (int)x, CTRL,
                                                       0xf, 0xf, false);
    return o < x ? o : x;
}

// full-wave unsigned-min; result valid in lane 63 only.
__device__ __forceinline__ unsigned wave_min_to_lane63(unsigned x) {
    x = umin_dpp<0x111>(x);   // row_shr:1
    x = umin_dpp<0x112>(x);   // row_shr:2
    x = umin_dpp<0x114>(x);   // row_shr:4
    x = umin_dpp<0x118>(x);   // row_shr:8  -> lane15 of each 16-row
    x = umin_dpp<0x142>(x);   // row_bcast:15
    x = umin_dpp<0x143>(x);   // row_bcast:31 -> lane63 = wave min
    return x;
}

__device__ __forceinline__ unsigned umin3(unsigned a, unsigned b, unsigned c) {
    unsigned t = a < b ? a : b;          // fuses to v_min3_u32
    return t < c ? t : c;
}

// biased key: coords pre-shifted <<5 so sdot2 gives d2<<10; acc = idx-1024
__device__ __forceinline__ unsigned mk_key(unsigned ps, unsigned qs, int izb) {
#if __has_builtin(__builtin_amdgcn_sdot2)
    v2s d = __builtin_bit_cast(v2s, ps) - __builtin_bit_cast(v2s, qs);
    return (unsigned)__builtin_amdgcn_sdot2(d, d, izb, false);
#else
    int dr = (int)(short)(ps >> 16) - (int)(short)(qs >> 16);
    int dc = (int)(short)(ps & 0xFFFFu) - (int)(short)(qs & 0xFFFFu);
    return (unsigned)(dr * dr + dc * dc + izb);
#endif
}

// uniform select of points[wslot][wlane] from 16 replicated regs
#define SEL16(P, res)                                                     \
    { unsigned _a0 = b0 ? P##1  : P##0;                                   \
      unsigned _a1 = b0 ? P##3  : P##2;                                   \
      unsigned _a2 = b0 ? P##5  : P##4;                                   \
      unsigned _a3 = b0 ? P##7  : P##6;                                   \
      unsigned _a4 = b0 ? P##9  : P##8;                                   \
      unsigned _a5 = b0 ? P##11 : P##10;                                  \
      unsigned _a6 = b0 ? P##13 : P##12;                                  \
      unsigned _a7 = b0 ? P##15 : P##14;                                  \
      unsigned _c0 = b1 ? _a1 : _a0;                                      \
      unsigned _c1 = b1 ? _a3 : _a2;                                      \
      unsigned _c2 = b1 ? _a5 : _a4;                                      \
      unsigned _c3 = b1 ? _a7 : _a6;                                      \
      unsigned _e0 = b2 ? _c1 : _c0;                                      \
      unsigned _e1 = b2 ? _c3 : _c2;                                      \
      res = b3 ? _e1 : _e0; }

#define LOADP(P, B)                                                       \
    unsigned P##0  = B[( 0 << 6) | lane] << 5;                            \
    unsigned P##1  = B[( 1 << 6) | lane] << 5;                            \
    unsigned P##2  = B[( 2 << 6) | lane] << 5;                            \
    unsigned P##3  = B[( 3 << 6) | lane] << 5;                            \
    unsigned P##4  = B[( 4 << 6) | lane] << 5;                            \
    unsigned P##5  = B[( 5 << 6) | lane] << 5;                            \
    unsigned P##6  = B[( 6 << 6) | lane] << 5;                            \
    unsigned P##7  = B[( 7 << 6) | lane] << 5;                            \
    unsigned P##8  = B[( 8 << 6) | lane] << 5;                            \
    unsigned P##9  = B[( 9 << 6) | lane] << 5;                            \
    unsigned P##10 = B[(10 << 6) | lane] << 5;                            \
    unsigned P##11 = B[(11 << 6) | lane] << 5;                            \
    unsigned P##12 = B[(12 << 6) | lane] << 5;                            \
    unsigned P##13 = B[(13 << 6) | lane] << 5;                            \
    unsigned P##14 = B[(14 << 6) | lane] << 5;                            \
    unsigned P##15 = B[(15 << 6) | lane] << 5;

__global__ __launch_bounds__(256, 1) void selmst_kernel(
        const unsigned long long* __restrict__ maskbits,
        unsigned* __restrict__ ptsG,
        unsigned* __restrict__ wsW) {
    __shared__ unsigned sP[KPTS];                 // LDS copy of packed points
    __shared__ unsigned swv[4];
    __shared__ __align__(16) unsigned xm[2][4];   // parity double-buffer
    int tid = threadIdx.x;
    int lane = tid & 63, wid = tid >> 6;
    int m = blockIdx.x;

    // ================= Phase A: select (identical logic) =================
    unsigned* ptsOut = ptsG + m * KPTS;
    for (int i = tid; i < KPTS; i += 256) { ptsOut[i] = 0u; sP[i] = 0u; }
    __syncthreads();

    unsigned running = 0;
    for (int ch = 0; ch < 16; ch++) {
        int w = ch * 256 + tid;
        unsigned long long word = maskbits[m * NWORDS + w];
        unsigned cnt = (unsigned)__popcll(word);

        unsigned x = cnt;                    // intra-wave inclusive scan
#pragma unroll
        for (int d = 1; d < 64; d <<= 1) {
            unsigned y = (unsigned)__shfl_up((int)x, d, 64);
            x += (lane >= d) ? y : 0u;
        }
        if (lane == 63) swv[wid] = x;
        __syncthreads();
        unsigned woff = 0, total = 0;
#pragma unroll
        for (int ww = 0; ww < 4; ww++) {
            unsigned tt = swv[ww];
            total += tt;
            woff += (ww < wid) ? tt : 0u;
        }
        unsigned rank = running + woff + x - cnt;   // exclusive prefix
        while (word) {
            int bpos = __builtin_ctzll(word);
            word &= word - 1;
            if (rank < (unsigned)KPTS) {
                unsigned pv = (unsigned)(w * 64 + bpos);
                unsigned packed = ((pv >> 9) << 16) | (pv & 511u);
                ptsOut[rank] = packed;
                sP[rank] = packed;
            }
            rank++;
        }
        running += total;
        if (running >= (unsigned)KPTS) break;   // uniform -> safe
        __syncthreads();   // protect swv before next chunk
    }
    __syncthreads();       // sP complete before mst phase reads it

    // block 0 zeroes the recover completion counter (its own region; its
    // select reads of this word — if any — are done; stream order
    // publishes the zero to the recover launch)
    if (m == 0 && tid == 0) wsW[CNT_WORD] = 0u;

    // ============ Phase B: mst (R1 structure, points from LDS) ===========
    unsigned pt0s = sP[0] << 5;      // self point 0, shifted (uniform)
    LOADP(p, sP)                     // replicated point set from LDS

    // this wave's 4 owned key slots: global slot = wid*4 + sl
    int oi0 = (((wid * 4 + 0) << 6) | lane) - 1024;
    int oi1 = (((wid * 4 + 1) << 6) | lane) - 1024;
    int oi2 = (((wid * 4 + 2) << 6) | lane) - 1024;
    int oi3 = (((wid * 4 + 3) << 6) | lane) - 1024;
    unsigned oq0 = sP[((wid * 4 + 0) << 6) | lane] << 5;
    unsigned oq1 = sP[((wid * 4 + 1) << 6) | lane] << 5;
    unsigned oq2 = sP[((wid * 4 + 2) << 6) | lane] << 5;
    unsigned oq3 = sP[((wid * 4 + 3) << 6) | lane] << 5;
    unsigned ok0 = mk_key(oq0, pt0s, oi0);   // node0 self-kills
    unsigned ok1 = mk_key(oq1, pt0s, oi1);
    unsigned ok2 = mk_key(oq2, pt0s, oi2);
    unsigned ok3 = mk_key(oq3, pt0s, oi3);

    unsigned* eout = wsW + m * IMGW;     // image m's OWN region (see header)
    unsigned r3i = umin3(ok0, ok1, ok2);
    unsigned rk = r3i < ok3 ? r3i : ok3;    // per-lane min over own 4 slots

    unsigned acc = 0;                // per-lane edge accumulator (batch of 64)
    int par = 0;

    for (int chk = 0; chk < 16; chk++) {
        int tmax = (chk < 15) ? 64 : 63;     // 15*64 + 63 = 1023 iterations
        for (int t = 0; t < tmax; t++) {
            // ---- per-wave reduce (6 DPP mins, result in lane63) ----
            unsigned wmin = wave_min_to_lane63(rk);
            if (lane == 63) xm[par][wid] = wmin;
            __syncthreads();

            // ---- cross-wave combine: broadcast b128 read of 4 minima ----
            u32x4 xv = *reinterpret_cast<const u32x4*>(&xm[par][0]);
            unsigned vm = umin3(xv.x, xv.y, xv.z);
            vm = vm < xv.w ? vm : xv.w;
            unsigned wk = (unsigned)__builtin_amdgcn_readfirstlane((int)vm) + 1024u;
            par ^= 1;

            unsigned j = wk & 1023u;
            int wslot = (int)(j >> 6);
            int wlane = (int)(j & 63u);

            // ---- pj (shifted coords) from replicated regs: SEL16+readlane --
            bool b0 = (wslot & 1) != 0, b1 = (wslot & 2) != 0;
            bool b2 = (wslot & 4) != 0, b3 = (wslot & 8) != 0;
            unsigned selPay;
            SEL16(p, selPay);
            unsigned pjs = (unsigned)__builtin_amdgcn_readlane((int)selPay, wlane);

            // ---- edge record: cndmask accumulate into lane t ----
            acc = (lane == t) ? wk : acc;

            // ---- decrease-key on own 4 slots; extracted slot self-kills ----
            { unsigned nk = mk_key(oq0, pjs, oi0);
              ok0 = (unsigned)min((int)ok0, (int)nk); }
            { unsigned nk = mk_key(oq1, pjs, oi1);
              ok1 = (unsigned)min((int)ok1, (int)nk); }
            { unsigned nk = mk_key(oq2, pjs, oi2);
              ok2 = (unsigned)min((int)ok2, (int)nk); }
            { unsigned nk = mk_key(oq3, pjs, oi3);
              ok3 = (unsigned)min((int)ok3, (int)nk); }
            unsigned r3 = umin3(ok0, ok1, ok2);
            rk = r3 < ok3 ? r3 : ok3;       // next iteration's per-lane min
        }
        // wave 0 does the full-wave coalesced batch store; chk=15 lane63
        // writes eout[1023] (stale value) which is never read downstream.
        // These bytes are image m's own maskbit chunks 0-1, already consumed
        // by THIS block's select phase -> no cross-block hazard.
        if (wid == 0) eout[(chk << 6) + lane] = acc;
    }
}

// ---------------------------------------------------------------------------
// Kernel 3 (FUSED recover + final): recover src per edge + (Dp-Dm)^2, then
// the LAST of the 256 blocks (device-scope atomic completion counter,
// release-fence / atomic / acquire-fence — the standard rocPRIM pattern,
// G16-safe) performs the final reduction with BIT-IDENTICAL arithmetic
// grouping to the previous final_kernel: per image, lane-l strided f64
// partials over e=i*64+l, shfl_xor butterfly d=32..1, sqrt; cross-image
// sum in image order by one thread. 4 waves x 4 images each.
// ---------------------------------------------------------------------------
__global__ __launch_bounds__(256) void recover_kernel(
        const unsigned* __restrict__ ptsG,
        unsigned* __restrict__ wsW,
        float* __restrict__ out) {
    __shared__ unsigned sS[KPTS];
    __shared__ unsigned sO[KPTS];
    __shared__ unsigned short sT[KPTS];   // extraction time + 1 (0 = root)
    __shared__ int isLast;
    __shared__ double part[NIMG];
    int g = blockIdx.x, m = blockIdx.y;
    int tid = threadIdx.x;
    int partner = m ^ 1;
    const unsigned* edges = wsW + m * IMGW;
    float* contrib = (float*)(wsW + m * IMGW + 2048);

    for (int i = tid; i < KPTS; i += 256) {
        sS[i] = ptsG[m * KPTS + i];
        sO[i] = ptsG[partner * KPTS + i];
    }
    for (int e = tid; e < KPTS - 1; e += 256) {
        unsigned wkk = edges[e];
        sT[wkk & 1023u] = (unsigned short)(e + 1);
    }
    if (tid == 0) sT[0] = 0;
    __syncthreads();

    int lane = tid & 63, w = tid >> 6;
    for (int k = 0; k < 16; k++) {
        int e = g * 64 + w * 16 + k;
        if (e >= KPTS - 1) break;            // only e=1023 (g=15,w=3,k=15)
        unsigned wk = edges[e];
        unsigned j = wk & 1023u;
        unsigned d2p = wk >> 10;
        unsigned pj = sS[j];
        unsigned te1 = (unsigned)(e + 1);

        unsigned best = 0xFFFFFFFFu;
#pragma unroll
        for (int i = 0; i < 16; i++) {
            int v = i * 64 + lane;
            unsigned pv = sS[v];
            int d2 = dist2_packed(pv, pj);
            unsigned tv1 = (unsigned)sT[v];
            bool qual = ((unsigned)d2 == d2p) && (tv1 < te1);
            unsigned cand = qual ? ((tv1 << 10) | (unsigned)v) : 0xFFFFFFFFu;
            best = cand < best ? cand : best;
        }
#pragma unroll
        for (int dd = 32; dd; dd >>= 1) {
            unsigned o = (unsigned)__shfl_xor((int)best, dd, 64);
            best = o < best ? o : best;
        }
        unsigned vsrc = best & 1023u;
        if (lane == 0) {
            unsigned oj = sO[j], os = sO[vsrc];
            float Dp = __fsqrt_rn((float)d2p);
            float Dm = __fsqrt_rn((float)dist2_packed(oj, os));
            float diff = Dp - Dm;
            contrib[e] = diff * diff;
        }
    }

    // ---- completion protocol: release fence -> counter; last block sums ----
    __threadfence();                 // publish this block's contrib writes
    __syncthreads();
    if (tid == 0) {
        unsigned old = atomicAdd(wsW + CNT_WORD, 1u);   // device scope
        isLast = (old == 255u) ? 1 : 0;
    }
    __syncthreads();
    if (!isLast) return;
    __threadfence();                 // acquire: see all blocks' contrib

    // final reduction (bit-identical grouping to the former final_kernel)
    for (int q = 0; q < 4; q++) {
        int img = w * 4 + q;
        const float* cb = (const float*)(wsW + img * IMGW + 2048);
        double s = 0.0;
#pragma unroll
        for (int i = 0; i < 16; i++) {
            int e = i * 64 + lane;
            s += (e < KPTS - 1) ? (double)cb[e] : 0.0;
        }
#pragma unroll
        for (int d = 32; d; d >>= 1)
            s += __shfl_xor(s, d, 64);
        if (lane == 0) part[img] = sqrt(s);
    }
    __syncthreads();
    if (tid == 0) {
        double tot = 0.0;
        for (int i = 0; i < NIMG; i++) tot += part[i];
        out[0] = (float)(0.1 * tot / 8.0);
    }
}

// ---------------------------------------------------------------------------
// ws layout (u32 words; per-image region = IMGW=8192 words = image m's own
// 32KB maskbit area):
//   [0,512K)bytes    maskbits (lbp->selmst); inside image m's region:
//     words [m*IMGW, m*IMGW+1024)        edges   (selmst->recover)
//     word  CNT_WORD (image 0 only)      recover completion counter
//     words [m*IMGW+2048, m*IMGW+3071)   contrib (recover->final phase)
//   [512K,576K)bytes ptsG (selmst->recover)
// ---------------------------------------------------------------------------
extern "C" void kernel_launch(void* const* d_in, const int* in_sizes, int n_in,
                              void* d_out, int out_size, void* d_ws, size_t ws_size,
                              hipStream_t stream) {
    const float* mo = (const float*)d_in[1];   // model_output
    const float* lb = (const float*)d_in[2];   // labels

    unsigned long long* maskbits = (unsigned long long*)d_ws;
    unsigned* wsW = (unsigned*)d_ws;
    unsigned* ptsG = (unsigned*)((char*)d_ws + (size_t)NIMG * NWORDS * 8);
    float* out = (float*)d_out;

    lbp_kernel<<<dim3(NPIX / 256, NIMG), 256, 0, stream>>>(mo, lb, maskbits);
    selmst_kernel<<<NIMG, 256, 0, stream>>>(maskbits, ptsG, wsW);
    recover_kernel<<<dim3(16, NIMG), 256, 0, stream>>>(ptsG, wsW, out);
}

// Round 13
// 391.645 us; speedup vs baseline: 1.0171x; 1.0171x over previous
//
#include <hip/hip_runtime.h>

#define HH 512
#define WW 512
#define NPIX (HH * WW)          // 262144
#define NIMG 16
#define KPTS 1024
#define NWORDS (NPIX / 64)      // 4096 u64 mask words per image
#define IMGW 8192               // u32 words per image region in ws (32 KB)

// ---------------------------------------------------------------------------
// Kernel 1: binarize + uniform LBP (P=8,R=1) — PURE BOOLEAN form.
// ---------------------------------------------------------------------------
__global__ void lbp_kernel(const float* __restrict__ mo,
                           const float* __restrict__ lb,
                           unsigned long long* __restrict__ maskbits) {
    int m = blockIdx.y;                    // image 0..15: even=pred, odd=mask
    int pix = blockIdx.x * blockDim.x + threadIdx.x;   // 0..262143
    int r = pix >> 9, c = pix & 511;
    int sample = m >> 1;
    const float* img = (m & 1) ? (lb + sample * NPIX) : (mo + sample * NPIX);
    float thr = (m & 1) ? 0.5f : 0.0f;     // sigmoid(x)>0.5 <=> x>0

    int rm = r - (r > 0), rp = r + (r < HH - 1);
    int cm = c - (c > 0), cp = c + (c < WW - 1);
    const float* rowm = img + rm * WW;
    const float* row0 = img + r  * WW;
    const float* rowp = img + rp * WW;

    bool bmm = rowm[cm] > thr, bm0 = rowm[c] > thr, bmp = rowm[cp] > thr;
    bool b0m = row0[cm] > thr, b00 = row0[c] > thr, b0p = row0[cp] > thr;
    bool bpm = rowp[cm] > thr, bp0 = rowp[c] > thr, bpp = rowp[cp] > thr;

    bool r0e = (r == 0), c0e = (c == 0);
    bool t2m = r0e ? bpm : b0m;    // B(row2, cm)
    bool t2c = r0e ? bp0 : b00;    // B(row2, c)
    bool t2p = r0e ? bpp : b0p;    // B(row2, cp)
    bool mc2 = c0e ? bmp : bm0;    // B(rm,  col2)
    bool tc2 = c0e ? t2p : t2c;    // B(row2,col2)
    bool zc2 = c0e ? b0p : b00;    // B(r,   col2)
    bool pc2 = c0e ? bpp : bp0;    // B(rp,  col2)

    unsigned bb =
        (b0p                     ?   1u : 0u)
      | ((bm0 & bmp & t2c & t2p) ?   2u : 0u)
      | (bm0                     ?   4u : 0u)
      | ((bmm & mc2 & t2m & tc2) ?   8u : 0u)
      | (b0m                     ?  16u : 0u)
      | ((b0m & zc2 & bpm & pc2) ?  32u : 0u)
      | (bp0                     ?  64u : 0u)
      | ((b0p & bp0 & bpp)       ? 128u : 0u);

    unsigned rol = ((bb << 1) | (bb >> 7)) & 0xFFu;
    int changes = __popc(bb ^ rol);
    int s = __popc(bb);
    bool maskbit = b00 && (changes <= 2) && (s < 5);   // lbp < THR(=5)

    unsigned long long w = __ballot(maskbit);
    if ((threadIdx.x & 63) == 0)
        maskbits[m * NWORDS + (pix >> 6)] = w;
}

// ---------------------------------------------------------------------------
// Kernel 2 (FUSED select + mst): grid 16 x 256.
//   Phase A (select): stable row-major compaction to K=1024 packed points,
//     written BOTH to global ptsG (for recover) and an LDS copy sP.
//   Phase B (mst): the proven R1 structure, bit-exact (657 cy/iter best of
//     9 measured variants), points from sP.
// WS RACE DISCIPLINE: edges for image m live INSIDE image m's own 32KB
// maskbit region (chunks 0-1, consumed by the same block's select phase
// before the mst phase writes them). contrib at words [2048,3071) of the
// same region, written only by recover.
// ---------------------------------------------------------------------------
typedef short v2s __attribute__((ext_vector_type(2)));
typedef unsigned u32x4 __attribute__((ext_vector_type(4)));

__device__ __forceinline__ int dist2_packed(unsigned a, unsigned b) {
#if __has_builtin(__builtin_amdgcn_sdot2)
    v2s d = __builtin_bit_cast(v2s, a) - __builtin_bit_cast(v2s, b);
    return __builtin_amdgcn_sdot2(d, d, 0, false);
#else
    int dr = (int)(a >> 16) - (int)(b >> 16);
    int dc = (int)(a & 0xFFFFu) - (int)(b & 0xFFFFu);
    return __mul24(dr, dr) + __mul24(dc, dc);
#endif
}

template <int CTRL>
__device__ __forceinline__ unsigned umin_dpp(unsigned x) {
    unsigned o = (unsigned)__builtin_amdgcn_update_dpp((int)x, (int)x, CTRL,
                                                       0xf, 0xf, false);
    return o < x ? o : x;
}

// full-wave unsigned-min; result valid in lane 63 only.
__device__ __forceinline__ unsigned wave_min_to_lane63(unsigned x) {
    x = umin_dpp<0x111>(x);   // row_shr:1
    x = umin_dpp<0x112>(x);   // row_shr:2
    x = umin_dpp<0x114>(x);   // row_shr:4
    x = umin_dpp<0x118>(x);   // row_shr:8  -> lane15 of each 16-row
    x = umin_dpp<0x142>(x);   // row_bcast:15
    x = umin_dpp<0x143>(x);   // row_bcast:31 -> lane63 = wave min
    return x;
}

__device__ __forceinline__ unsigned umin3(unsigned a, unsigned b, unsigned c) {
    unsigned t = a < b ? a : b;          // fuses to v_min3_u32
    return t < c ? t : c;
}

// biased key: coords pre-shifted <<5 so sdot2 gives d2<<10; acc = idx-1024
__device__ __forceinline__ unsigned mk_key(unsigned ps, unsigned qs, int izb) {
#if __has_builtin(__builtin_amdgcn_sdot2)
    v2s d = __builtin_bit_cast(v2s, ps) - __builtin_bit_cast(v2s, qs);
    return (unsigned)__builtin_amdgcn_sdot2(d, d, izb, false);
#else
    int dr = (int)(short)(ps >> 16) - (int)(short)(qs >> 16);
    int dc = (int)(short)(ps & 0xFFFFu) - (int)(short)(qs & 0xFFFFu);
    return (unsigned)(dr * dr + dc * dc + izb);
#endif
}

// uniform select of points[wslot][wlane] from 16 replicated regs
#define SEL16(P, res)                                                     \
    { unsigned _a0 = b0 ? P##1  : P##0;                                   \
      unsigned _a1 = b0 ? P##3  : P##2;                                   \
      unsigned _a2 = b0 ? P##5  : P##4;                                   \
      unsigned _a3 = b0 ? P##7  : P##6;                                   \
      unsigned _a4 = b0 ? P##9  : P##8;                                   \
      unsigned _a5 = b0 ? P##11 : P##10;                                  \
      unsigned _a6 = b0 ? P##13 : P##12;                                  \
      unsigned _a7 = b0 ? P##15 : P##14;                                  \
      unsigned _c0 = b1 ? _a1 : _a0;                                      \
      unsigned _c1 = b1 ? _a3 : _a2;                                      \
      unsigned _c2 = b1 ? _a5 : _a4;                                      \
      unsigned _c3 = b1 ? _a7 : _a6;                                      \
      unsigned _e0 = b2 ? _c1 : _c0;                                      \
      unsigned _e1 = b2 ? _c3 : _c2;                                      \
      res = b3 ? _e1 : _e0; }

#define LOADP(P, B)                                                       \
    unsigned P##0  = B[( 0 << 6) | lane] << 5;                            \
    unsigned P##1  = B[( 1 << 6) | lane] << 5;                            \
    unsigned P##2  = B[( 2 << 6) | lane] << 5;                            \
    unsigned P##3  = B[( 3 << 6) | lane] << 5;                            \
    unsigned P##4  = B[( 4 << 6) | lane] << 5;                            \
    unsigned P##5  = B[( 5 << 6) | lane] << 5;                            \
    unsigned P##6  = B[( 6 << 6) | lane] << 5;                            \
    unsigned P##7  = B[( 7 << 6) | lane] << 5;                            \
    unsigned P##8  = B[( 8 << 6) | lane] << 5;                            \
    unsigned P##9  = B[( 9 << 6) | lane] << 5;                            \
    unsigned P##10 = B[(10 << 6) | lane] << 5;                            \
    unsigned P##11 = B[(11 << 6) | lane] << 5;                            \
    unsigned P##12 = B[(12 << 6) | lane] << 5;                            \
    unsigned P##13 = B[(13 << 6) | lane] << 5;                            \
    unsigned P##14 = B[(14 << 6) | lane] << 5;                            \
    unsigned P##15 = B[(15 << 6) | lane] << 5;

__global__ __launch_bounds__(256, 1) void selmst_kernel(
        const unsigned long long* __restrict__ maskbits,
        unsigned* __restrict__ ptsG,
        unsigned* __restrict__ wsW) {
    __shared__ unsigned sP[KPTS];                 // LDS copy of packed points
    __shared__ unsigned swv[4];
    __shared__ __align__(16) unsigned xm[2][4];   // parity double-buffer
    int tid = threadIdx.x;
    int lane = tid & 63, wid = tid >> 6;
    int m = blockIdx.x;

    // ================= Phase A: select (identical logic) =================
    unsigned* ptsOut = ptsG + m * KPTS;
    for (int i = tid; i < KPTS; i += 256) { ptsOut[i] = 0u; sP[i] = 0u; }
    __syncthreads();

    unsigned running = 0;
    for (int ch = 0; ch < 16; ch++) {
        int w = ch * 256 + tid;
        unsigned long long word = maskbits[m * NWORDS + w];
        unsigned cnt = (unsigned)__popcll(word);

        unsigned x = cnt;                    // intra-wave inclusive scan
#pragma unroll
        for (int d = 1; d < 64; d <<= 1) {
            unsigned y = (unsigned)__shfl_up((int)x, d, 64);
            x += (lane >= d) ? y : 0u;
        }
        if (lane == 63) swv[wid] = x;
        __syncthreads();
        unsigned woff = 0, total = 0;
#pragma unroll
        for (int ww = 0; ww < 4; ww++) {
            unsigned tt = swv[ww];
            total += tt;
            woff += (ww < wid) ? tt : 0u;
        }
        unsigned rank = running + woff + x - cnt;   // exclusive prefix
        while (word) {
            int bpos = __builtin_ctzll(word);
            word &= word - 1;
            if (rank < (unsigned)KPTS) {
                unsigned pv = (unsigned)(w * 64 + bpos);
                unsigned packed = ((pv >> 9) << 16) | (pv & 511u);
                ptsOut[rank] = packed;
                sP[rank] = packed;
            }
            rank++;
        }
        running += total;
        if (running >= (unsigned)KPTS) break;   // uniform -> safe
        __syncthreads();   // protect swv before next chunk
    }
    __syncthreads();       // sP complete before mst phase reads it

    // ============ Phase B: mst (R1 structure, points from LDS) ===========
    unsigned pt0s = sP[0] << 5;      // self point 0, shifted (uniform)
    LOADP(p, sP)                     // replicated point set from LDS

    // this wave's 4 owned key slots: global slot = wid*4 + sl
    int oi0 = (((wid * 4 + 0) << 6) | lane) - 1024;
    int oi1 = (((wid * 4 + 1) << 6) | lane) - 1024;
    int oi2 = (((wid * 4 + 2) << 6) | lane) - 1024;
    int oi3 = (((wid * 4 + 3) << 6) | lane) - 1024;
    unsigned oq0 = sP[((wid * 4 + 0) << 6) | lane] << 5;
    unsigned oq1 = sP[((wid * 4 + 1) << 6) | lane] << 5;
    unsigned oq2 = sP[((wid * 4 + 2) << 6) | lane] << 5;
    unsigned oq3 = sP[((wid * 4 + 3) << 6) | lane] << 5;
    unsigned ok0 = mk_key(oq0, pt0s, oi0);   // node0 self-kills
    unsigned ok1 = mk_key(oq1, pt0s, oi1);
    unsigned ok2 = mk_key(oq2, pt0s, oi2);
    unsigned ok3 = mk_key(oq3, pt0s, oi3);

    unsigned* eout = wsW + m * IMGW;     // image m's OWN region (see header)
    unsigned r3i = umin3(ok0, ok1, ok2);
    unsigned rk = r3i < ok3 ? r3i : ok3;    // per-lane min over own 4 slots

    unsigned acc = 0;                // per-lane edge accumulator (batch of 64)
    int par = 0;

    for (int chk = 0; chk < 16; chk++) {
        int tmax = (chk < 15) ? 64 : 63;     // 15*64 + 63 = 1023 iterations
        for (int t = 0; t < tmax; t++) {
            // ---- per-wave reduce (6 DPP mins, result in lane63) ----
            unsigned wmin = wave_min_to_lane63(rk);
            if (lane == 63) xm[par][wid] = wmin;
            __syncthreads();

            // ---- cross-wave combine: broadcast b128 read of 4 minima ----
            u32x4 xv = *reinterpret_cast<const u32x4*>(&xm[par][0]);
            unsigned vm = umin3(xv.x, xv.y, xv.z);
            vm = vm < xv.w ? vm : xv.w;
            unsigned wk = (unsigned)__builtin_amdgcn_readfirstlane((int)vm) + 1024u;
            par ^= 1;

            unsigned j = wk & 1023u;
            int wslot = (int)(j >> 6);
            int wlane = (int)(j & 63u);

            // ---- pj (shifted coords) from replicated regs: SEL16+readlane --
            bool b0 = (wslot & 1) != 0, b1 = (wslot & 2) != 0;
            bool b2 = (wslot & 4) != 0, b3 = (wslot & 8) != 0;
            unsigned selPay;
            SEL16(p, selPay);
            unsigned pjs = (unsigned)__builtin_amdgcn_readlane((int)selPay, wlane);

            // ---- edge record: cndmask accumulate into lane t ----
            acc = (lane == t) ? wk : acc;

            // ---- decrease-key on own 4 slots; extracted slot self-kills ----
            { unsigned nk = mk_key(oq0, pjs, oi0);
              ok0 = (unsigned)min((int)ok0, (int)nk); }
            { unsigned nk = mk_key(oq1, pjs, oi1);
              ok1 = (unsigned)min((int)ok1, (int)nk); }
            { unsigned nk = mk_key(oq2, pjs, oi2);
              ok2 = (unsigned)min((int)ok2, (int)nk); }
            { unsigned nk = mk_key(oq3, pjs, oi3);
              ok3 = (unsigned)min((int)ok3, (int)nk); }
            unsigned r3 = umin3(ok0, ok1, ok2);
            rk = r3 < ok3 ? r3 : ok3;       // next iteration's per-lane min
        }
        // wave 0 does the full-wave coalesced batch store; chk=15 lane63
        // writes eout[1023] (stale value) which is never read downstream.
        // These bytes are image m's own maskbit chunks 0-1, already consumed
        // by THIS block's select phase -> no cross-block hazard.
        if (wid == 0) eout[(chk << 6) + lane] = acc;
    }
}

// ---------------------------------------------------------------------------
// Kernel 3 (phase 2): recover src per edge + per-edge (Dp-Dm)^2.
// edges at wsW + m*IMGW, contrib at wsW + m*IMGW + 2048 (f32).
// ---------------------------------------------------------------------------
__global__ void recover_kernel(const unsigned* __restrict__ ptsG,
                               unsigned* __restrict__ wsW) {
    __shared__ unsigned sS[KPTS];
    __shared__ unsigned sO[KPTS];
    __shared__ unsigned short sT[KPTS];   // extraction time + 1 (0 = root)
    int g = blockIdx.x, m = blockIdx.y;
    int tid = threadIdx.x;
    int partner = m ^ 1;
    const unsigned* edges = wsW + m * IMGW;
    float* contrib = (float*)(wsW + m * IMGW + 2048);

    for (int i = tid; i < KPTS; i += 256) {
        sS[i] = ptsG[m * KPTS + i];
        sO[i] = ptsG[partner * KPTS + i];
    }
    for (int e = tid; e < KPTS - 1; e += 256) {
        unsigned wkk = edges[e];
        sT[wkk & 1023u] = (unsigned short)(e + 1);
    }
    if (tid == 0) sT[0] = 0;
    __syncthreads();

    int lane = tid & 63, w = tid >> 6;
    for (int k = 0; k < 16; k++) {
        int e = g * 64 + w * 16 + k;
        if (e >= KPTS - 1) break;            // only e=1023 (g=15,w=3,k=15)
        unsigned wk = edges[e];
        unsigned j = wk & 1023u;
        unsigned d2p = wk >> 10;
        unsigned pj = sS[j];
        unsigned te1 = (unsigned)(e + 1);

        unsigned best = 0xFFFFFFFFu;
#pragma unroll
        for (int i = 0; i < 16; i++) {
            int v = i * 64 + lane;
            unsigned pv = sS[v];
            int d2 = dist2_packed(pv, pj);
            unsigned tv1 = (unsigned)sT[v];
            bool qual = ((unsigned)d2 == d2p) && (tv1 < te1);
            unsigned cand = qual ? ((tv1 << 10) | (unsigned)v) : 0xFFFFFFFFu;
            best = cand < best ? cand : best;
        }
#pragma unroll
        for (int dd = 32; dd; dd >>= 1) {
            unsigned o = (unsigned)__shfl_xor((int)best, dd, 64);
            best = o < best ? o : best;
        }
        unsigned vsrc = best & 1023u;
        if (lane == 0) {
            unsigned oj = sO[j], os = sO[vsrc];
            float Dp = __fsqrt_rn((float)d2p);
            float Dm = __fsqrt_rn((float)dist2_packed(oj, os));
            float diff = Dp - Dm;
            contrib[e] = diff * diff;
        }
    }
}

// ---------------------------------------------------------------------------
// Kernel 4: final reduction, PARALLELIZED (R11, confirmed +15 µs vs serial).
// 1024 threads = 16 waves; wave w owns image w; lane l sums e = i*64+l
// (coalesced), f64 shfl_xor butterfly, sqrt; cross-image sum in image order.
// ---------------------------------------------------------------------------
__global__ __launch_bounds__(1024, 1) void final_kernel(
        const unsigned* __restrict__ wsW,
        float* __restrict__ out) {
    __shared__ double part[NIMG];
    int tid = threadIdx.x;           // 0..1023
    int lane = tid & 63, w = tid >> 6;   // w = image 0..15
    const float* contrib = (const float*)(wsW + w * IMGW + 2048);

    double s = 0.0;
#pragma unroll
    for (int i = 0; i < 16; i++) {
        int e = i * 64 + lane;
        s += (e < KPTS - 1) ? (double)contrib[e] : 0.0;
    }
#pragma unroll
    for (int d = 32; d; d >>= 1)
        s += __shfl_xor(s, d, 64);
    if (lane == 0) part[w] = sqrt(s);
    __syncthreads();
    if (tid == 0) {
        double tot = 0.0;
        for (int i = 0; i < NIMG; i++) tot += part[i];
        out[0] = (float)(0.1 * tot / 8.0);
    }
}

// ---------------------------------------------------------------------------
// ws layout (u32 words; per-image region = IMGW=8192 words = image m's own
// 32KB maskbit area):
//   [0,512K)bytes    maskbits (lbp->selmst); inside image m's region:
//     words [m*IMGW, m*IMGW+1024)        edges   (selmst->recover; overwrites
//                                        m's own chunks 0-1, post-consumption)
//     words [m*IMGW+2048, m*IMGW+3071)   contrib (recover->final)
//   [512K,576K)bytes ptsG (selmst->recover)
// ---------------------------------------------------------------------------
extern "C" void kernel_launch(void* const* d_in, const int* in_sizes, int n_in,
                              void* d_out, int out_size, void* d_ws, size_t ws_size,
                              hipStream_t stream) {
    const float* mo = (const float*)d_in[1];   // model_output
    const float* lb = (const float*)d_in[2];   // labels

    unsigned long long* maskbits = (unsigned long long*)d_ws;
    unsigned* wsW = (unsigned*)d_ws;
    unsigned* ptsG = (unsigned*)((char*)d_ws + (size_t)NIMG * NWORDS * 8);
    float* out = (float*)d_out;

    lbp_kernel<<<dim3(NPIX / 256, NIMG), 256, 0, stream>>>(mo, lb, maskbits);
    selmst_kernel<<<NIMG, 256, 0, stream>>>(maskbits, ptsG, wsW);
    recover_kernel<<<dim3(16, NIMG), 256, 0, stream>>>(ptsG, wsW);
    final_kernel<<<1, 1024, 0, stream>>>(wsW, out);
}